// Round 2
// baseline (5970.177 us; speedup 1.0000x reference)
//
#include <hip/hip_runtime.h>
#include <stdint.h>

#define F_IN 512
#define HF 256
#define OUT_F 2
#define BN_EPS 1e-5f

// ---------- degree / norm ----------
__global__ void init_deg_kernel(float* __restrict__ deg, int n) {
    int i = blockIdx.x * blockDim.x + threadIdx.x;
    if (i < n) deg[i] = 1.0f;   // self-loop weight
}

__global__ void deg_accum_kernel(const int* __restrict__ col,
                                 const float* __restrict__ w,
                                 float* __restrict__ deg, int e) {
    int i = blockIdx.x * blockDim.x + threadIdx.x;
    if (i < e) atomicAdd(&deg[col[i]], w[i]);
}

__global__ void dinv_kernel(float* __restrict__ deg, int n) {
    int i = blockIdx.x * blockDim.x + threadIdx.x;
    if (i < n) {
        float d = deg[i];
        deg[i] = d > 0.0f ? rsqrtf(d) : 0.0f;   // in-place: deg -> dinv
    }
}

// ---------- fp32 tiled GEMM: C[M,Nc] = A[M,K] @ B[K,Nc] ----------
// BM=BN=64, BK=16, 256 threads, 4x4 micro-tile per thread.
__global__ void sgemm_kernel(const float* __restrict__ A, const float* __restrict__ B,
                             float* __restrict__ C, int M, int K, int Nc) {
    const int BM = 64, BN = 64, BK = 16;
    __shared__ float As[BK][BM + 4];
    __shared__ float Bs[BK][BN];
    int tid = threadIdx.x;
    int tx = tid & 15, ty = tid >> 4;
    int m0 = blockIdx.x * BM;
    int n0 = blockIdx.y * BN;

    float acc[4][4] = {};

    for (int k0 = 0; k0 < K; k0 += BK) {
        // A tile: 64 rows x 16 k, one float4 per thread, transposed into LDS
        {
            int arow = tid >> 2;          // 0..63
            int ak   = (tid & 3) * 4;     // 0,4,8,12
            float4 av = make_float4(0.f, 0.f, 0.f, 0.f);
            int gm = m0 + arow;
            if (gm < M) av = *(const float4*)(A + (size_t)gm * K + k0 + ak);
            As[ak + 0][arow] = av.x;
            As[ak + 1][arow] = av.y;
            As[ak + 2][arow] = av.z;
            As[ak + 3][arow] = av.w;
        }
        // B tile: 16 k x 64 cols, one float4 per thread
        {
            int brow = tid >> 4;          // 0..15
            int bn   = (tid & 15) * 4;
            float4 bv = *(const float4*)(B + (size_t)(k0 + brow) * Nc + n0 + bn);
            *(float4*)&Bs[brow][bn] = bv;
        }
        __syncthreads();
        #pragma unroll
        for (int kk = 0; kk < BK; ++kk) {
            float a4[4], b4[4];
            #pragma unroll
            for (int i = 0; i < 4; ++i) a4[i] = As[kk][ty * 4 + i];
            #pragma unroll
            for (int j = 0; j < 4; ++j) b4[j] = Bs[kk][tx * 4 + j];
            #pragma unroll
            for (int i = 0; i < 4; ++i)
                #pragma unroll
                for (int j = 0; j < 4; ++j)
                    acc[i][j] += a4[i] * b4[j];
        }
        __syncthreads();
    }

    #pragma unroll
    for (int i = 0; i < 4; ++i) {
        int gm = m0 + ty * 4 + i;
        if (gm < M) {
            float4 cv = make_float4(acc[i][0], acc[i][1], acc[i][2], acc[i][3]);
            *(float4*)(C + (size_t)gm * Nc + n0 + tx * 4) = cv;
        }
    }
}

// ---------- edge scatter, 256 features: agg[col] += norm * h[row] ----------
// one wave (64 lanes) per edge, 4 features (float4) per lane
__global__ void scatter_h_kernel(const float* __restrict__ h,
                                 const int* __restrict__ row,
                                 const int* __restrict__ col,
                                 const float* __restrict__ w,
                                 const float* __restrict__ dinv,
                                 float* __restrict__ agg, int e) {
    int gid  = blockIdx.x * blockDim.x + threadIdx.x;
    int wave = gid >> 6;
    int lane = gid & 63;
    if (wave >= e) return;
    int r = row[wave];
    int c = col[wave];
    float norm = dinv[r] * w[wave] * dinv[c];
    float4 hv = *(const float4*)(h + (size_t)r * HF + lane * 4);
    float* dst = agg + (size_t)c * HF + lane * 4;
    atomicAdd(dst + 0, norm * hv.x);
    atomicAdd(dst + 1, norm * hv.y);
    atomicAdd(dst + 2, norm * hv.z);
    atomicAdd(dst + 3, norm * hv.w);
}

// ---------- epilogue: a = relu(bn(agg + selfloop + bias)) ----------
__global__ void epilogue_kernel(float* __restrict__ a,         // in: agg, out: activation
                                const float* __restrict__ h,   // pre-aggregation features
                                const float* __restrict__ dinv,
                                const float* __restrict__ b, const float* __restrict__ g,
                                const float* __restrict__ be, const float* __restrict__ m,
                                const float* __restrict__ v, int n) {
    int i = blockIdx.x * blockDim.x + threadIdx.x;
    if (i < n * HF) {
        int node = i >> 8;
        int f = i & (HF - 1);
        float s = dinv[node];
        float val = a[i] + h[i] * s * s + b[f];
        val = (val - m[f]) * rsqrtf(v[f] + BN_EPS) * g[f] + be[f];
        a[i] = fmaxf(val, 0.0f);
    }
}

// ---------- layer 3 GEMV: h3[N,2] = a[N,256] @ W3[256,2] ----------
// one wave per node
__global__ void gemv_out_kernel(const float* __restrict__ a, const float* __restrict__ W3,
                                float* __restrict__ h3, int n) {
    int gid = blockIdx.x * blockDim.x + threadIdx.x;
    int node = gid >> 6;
    int lane = gid & 63;
    if (node >= n) return;
    float4 av = *(const float4*)(a + (size_t)node * HF + lane * 4);
    int k = lane * 4;
    float acc0 = av.x * W3[(k + 0) * 2 + 0] + av.y * W3[(k + 1) * 2 + 0]
               + av.z * W3[(k + 2) * 2 + 0] + av.w * W3[(k + 3) * 2 + 0];
    float acc1 = av.x * W3[(k + 0) * 2 + 1] + av.y * W3[(k + 1) * 2 + 1]
               + av.z * W3[(k + 2) * 2 + 1] + av.w * W3[(k + 3) * 2 + 1];
    #pragma unroll
    for (int o = 32; o > 0; o >>= 1) {
        acc0 += __shfl_down(acc0, o, 64);
        acc1 += __shfl_down(acc1, o, 64);
    }
    if (lane == 0) {
        h3[node * 2 + 0] = acc0;
        h3[node * 2 + 1] = acc1;
    }
}

// ---------- final scatter (2 features) ----------
__global__ void scatter_out_kernel(const float* __restrict__ h3,
                                   const int* __restrict__ row,
                                   const int* __restrict__ col,
                                   const float* __restrict__ w,
                                   const float* __restrict__ dinv,
                                   float* __restrict__ out, int e) {
    int ed = blockIdx.x * blockDim.x + threadIdx.x;
    if (ed < e) {
        int r = row[ed];
        int c = col[ed];
        float norm = dinv[r] * w[ed] * dinv[c];
        atomicAdd(out + c * 2 + 0, norm * h3[r * 2 + 0]);
        atomicAdd(out + c * 2 + 1, norm * h3[r * 2 + 1]);
    }
}

__global__ void final_epilogue_kernel(float* __restrict__ out, const float* __restrict__ h3,
                                      const float* __restrict__ dinv,
                                      const float* __restrict__ b3, int n) {
    int i = blockIdx.x * blockDim.x + threadIdx.x;
    if (i < n * 2) {
        int node = i >> 1;
        int f = i & 1;
        float s = dinv[node];
        out[i] += h3[i] * s * s + b3[f];
    }
}

extern "C" void kernel_launch(void* const* d_in, const int* in_sizes, int n_in,
                              void* d_out, int out_size, void* d_ws, size_t ws_size,
                              hipStream_t stream) {
    const float* x   = (const float*)d_in[0];
    const int*   ei  = (const int*)d_in[1];    // int64 in reference -> int32 in harness
    const float* ew  = (const float*)d_in[2];
    const float* W1  = (const float*)d_in[3];
    const float* b1  = (const float*)d_in[4];
    const float* g1  = (const float*)d_in[5];
    const float* be1 = (const float*)d_in[6];
    const float* m1  = (const float*)d_in[7];
    const float* v1  = (const float*)d_in[8];
    const float* W2  = (const float*)d_in[9];
    const float* b2  = (const float*)d_in[10];
    const float* g2  = (const float*)d_in[11];
    const float* be2 = (const float*)d_in[12];
    const float* m2  = (const float*)d_in[13];
    const float* v2  = (const float*)d_in[14];
    const float* W3  = (const float*)d_in[15];
    const float* b3  = (const float*)d_in[16];

    const int N = in_sizes[0] / F_IN;
    const int E = in_sizes[2];
    const int* row = ei;       // edge_index[0]
    const int* col = ei + E;   // edge_index[1]

    float* ws   = (float*)d_ws;
    float* dinv = ws;                          // N  (deg then dinv, in place)
    float* buf1 = dinv + N;                    // N*HF
    float* buf2 = buf1 + (size_t)N * HF;       // N*HF
    float* h3   = buf2 + (size_t)N * HF;       // N*2
    float* outf = (float*)d_out;

    const int TB = 256;

    // --- degree / dinv (graph identical across layers, compute once) ---
    init_deg_kernel<<<(N + TB - 1) / TB, TB, 0, stream>>>(dinv, N);
    deg_accum_kernel<<<(E + TB - 1) / TB, TB, 0, stream>>>(col, ew, dinv, E);
    dinv_kernel<<<(N + TB - 1) / TB, TB, 0, stream>>>(dinv, N);

    dim3 gemm_grid((N + 63) / 64, HF / 64);

    // --- layer 1 ---
    sgemm_kernel<<<gemm_grid, TB, 0, stream>>>(x, W1, buf1, N, F_IN, HF);
    hipMemsetAsync(buf2, 0, (size_t)N * HF * sizeof(float), stream);
    scatter_h_kernel<<<((size_t)E * 64 + TB - 1) / TB, TB, 0, stream>>>(buf1, row, col, ew, dinv, buf2, E);
    epilogue_kernel<<<((size_t)N * HF + TB - 1) / TB, TB, 0, stream>>>(buf2, buf1, dinv, b1, g1, be1, m1, v1, N);

    // --- layer 2 ---
    sgemm_kernel<<<gemm_grid, TB, 0, stream>>>(buf2, W2, buf1, N, HF, HF);
    hipMemsetAsync(buf2, 0, (size_t)N * HF * sizeof(float), stream);
    scatter_h_kernel<<<((size_t)E * 64 + TB - 1) / TB, TB, 0, stream>>>(buf1, row, col, ew, dinv, buf2, E);
    epilogue_kernel<<<((size_t)N * HF + TB - 1) / TB, TB, 0, stream>>>(buf2, buf1, dinv, b2, g2, be2, m2, v2, N);

    // --- layer 3 ---
    gemv_out_kernel<<<((size_t)N * 64 + TB - 1) / TB, TB, 0, stream>>>(buf2, W3, h3, N);
    hipMemsetAsync(outf, 0, (size_t)N * OUT_F * sizeof(float), stream);
    scatter_out_kernel<<<(E + TB - 1) / TB, TB, 0, stream>>>(h3, row, col, ew, dinv, outf, E);
    final_epilogue_kernel<<<(N * OUT_F + TB - 1) / TB, TB, 0, stream>>>(outf, h3, dinv, b3, N);
}

// Round 3
// 860.521 us; speedup vs baseline: 6.9379x; 6.9379x over previous
//
#include <hip/hip_runtime.h>
#include <stdint.h>

#define F_IN 512
#define HF 256
#define OUT_F 2
#define BN_EPS 1e-5f
#define SCAN_B 256

// ---------- degree + histogram ----------
__global__ void init_deg_kernel(float* __restrict__ deg, int n) {
    int i = blockIdx.x * blockDim.x + threadIdx.x;
    if (i < n) deg[i] = 1.0f;   // self-loop weight
}

__global__ void count_deg_kernel(const int* __restrict__ col,
                                 const float* __restrict__ w,
                                 float* __restrict__ deg,
                                 int* __restrict__ hist, int e) {
    int i = blockIdx.x * blockDim.x + threadIdx.x;
    if (i < e) {
        int c = col[i];
        atomicAdd(&deg[c], w[i]);
        atomicAdd(&hist[c], 1);
    }
}

__global__ void dinv_kernel(float* __restrict__ deg, int n) {
    int i = blockIdx.x * blockDim.x + threadIdx.x;
    if (i < n) {
        float d = deg[i];
        deg[i] = d > 0.0f ? rsqrtf(d) : 0.0f;   // in-place: deg -> dinv
    }
}

// ---------- hierarchical exclusive scan (hist -> csr_ptr) ----------
__global__ void scan1_kernel(const int* __restrict__ hist, int* __restrict__ local,
                             int* __restrict__ blocksum, int n) {
    __shared__ int tmp[SCAN_B];
    int i = blockIdx.x * SCAN_B + threadIdx.x;
    int v = (i < n) ? hist[i] : 0;
    tmp[threadIdx.x] = v;
    __syncthreads();
    for (int off = 1; off < SCAN_B; off <<= 1) {
        int t = 0;
        if ((int)threadIdx.x >= off) t = tmp[threadIdx.x - off];
        __syncthreads();
        if ((int)threadIdx.x >= off) tmp[threadIdx.x] += t;
        __syncthreads();
    }
    if (i < n) local[i] = tmp[threadIdx.x] - v;       // exclusive
    if (threadIdx.x == SCAN_B - 1) blocksum[blockIdx.x] = tmp[SCAN_B - 1];
}

__global__ void scan2_kernel(int* __restrict__ blocksum, int nb) {
    __shared__ int tmp[SCAN_B];
    int v = ((int)threadIdx.x < nb) ? blocksum[threadIdx.x] : 0;
    tmp[threadIdx.x] = v;
    __syncthreads();
    for (int off = 1; off < SCAN_B; off <<= 1) {
        int t = 0;
        if ((int)threadIdx.x >= off) t = tmp[threadIdx.x - off];
        __syncthreads();
        if ((int)threadIdx.x >= off) tmp[threadIdx.x] += t;
        __syncthreads();
    }
    if ((int)threadIdx.x < nb) blocksum[threadIdx.x] = tmp[threadIdx.x] - v;   // exclusive
}

__global__ void scan3_kernel(int* __restrict__ csr_ptr, int* __restrict__ cursor,
                             const int* __restrict__ blocksum, int n, int e) {
    int i = blockIdx.x * SCAN_B + threadIdx.x;
    if (i < n) {
        int val = csr_ptr[i] + blocksum[blockIdx.x];
        csr_ptr[i] = val;
        cursor[i] = val;
    }
    if (i == 0) csr_ptr[n] = e;
}

// ---------- CSR fill: bucket edges by col, fold norm ----------
__global__ void fill_kernel(const int* __restrict__ row, const int* __restrict__ col,
                            const float* __restrict__ w, const float* __restrict__ dinv,
                            int* __restrict__ cursor, int* __restrict__ csr_src,
                            float* __restrict__ csr_norm, int e) {
    int i = blockIdx.x * blockDim.x + threadIdx.x;
    if (i < e) {
        int r = row[i], c = col[i];
        int pos = atomicAdd(&cursor[c], 1);
        csr_src[pos] = r;
        csr_norm[pos] = dinv[r] * w[i] * dinv[c];
    }
}

// ---------- fp32 tiled GEMM: C[M,Nc] = A[M,K] @ B[K,Nc] ----------
__global__ void sgemm_kernel(const float* __restrict__ A, const float* __restrict__ B,
                             float* __restrict__ C, int M, int K, int Nc) {
    const int BM = 64, BN = 64, BK = 16;
    __shared__ float As[BK][BM + 4];
    __shared__ float Bs[BK][BN];
    int tid = threadIdx.x;
    int tx = tid & 15, ty = tid >> 4;
    int m0 = blockIdx.x * BM;
    int n0 = blockIdx.y * BN;

    float acc[4][4] = {};

    for (int k0 = 0; k0 < K; k0 += BK) {
        {
            int arow = tid >> 2;
            int ak   = (tid & 3) * 4;
            float4 av = make_float4(0.f, 0.f, 0.f, 0.f);
            int gm = m0 + arow;
            if (gm < M) av = *(const float4*)(A + (size_t)gm * K + k0 + ak);
            As[ak + 0][arow] = av.x;
            As[ak + 1][arow] = av.y;
            As[ak + 2][arow] = av.z;
            As[ak + 3][arow] = av.w;
        }
        {
            int brow = tid >> 4;
            int bn   = (tid & 15) * 4;
            float4 bv = *(const float4*)(B + (size_t)(k0 + brow) * Nc + n0 + bn);
            *(float4*)&Bs[brow][bn] = bv;
        }
        __syncthreads();
        #pragma unroll
        for (int kk = 0; kk < BK; ++kk) {
            float a4[4], b4[4];
            #pragma unroll
            for (int i = 0; i < 4; ++i) a4[i] = As[kk][ty * 4 + i];
            #pragma unroll
            for (int j = 0; j < 4; ++j) b4[j] = Bs[kk][tx * 4 + j];
            #pragma unroll
            for (int i = 0; i < 4; ++i)
                #pragma unroll
                for (int j = 0; j < 4; ++j)
                    acc[i][j] += a4[i] * b4[j];
        }
        __syncthreads();
    }

    #pragma unroll
    for (int i = 0; i < 4; ++i) {
        int gm = m0 + ty * 4 + i;
        if (gm < M) {
            float4 cv = make_float4(acc[i][0], acc[i][1], acc[i][2], acc[i][3]);
            *(float4*)(C + (size_t)gm * Nc + n0 + tx * 4) = cv;
        }
    }
}

// ---------- fused CSR gather + self-loop + bias + BN + ReLU ----------
// one wave per node, lane handles 4 consecutive features (float4)
__global__ void agg_bn_relu_kernel(const float* __restrict__ h,
                                   const int* __restrict__ ptr,
                                   const int* __restrict__ src,
                                   const float* __restrict__ nrm,
                                   const float* __restrict__ dinv,
                                   const float* __restrict__ b, const float* __restrict__ g,
                                   const float* __restrict__ be, const float* __restrict__ m,
                                   const float* __restrict__ v,
                                   float* __restrict__ out, int n) {
    int wid  = (blockIdx.x * blockDim.x + threadIdx.x) >> 6;
    int lane = threadIdx.x & 63;
    if (wid >= n) return;
    int p0 = ptr[wid], p1 = ptr[wid + 1];
    float4 acc = make_float4(0.f, 0.f, 0.f, 0.f);
    for (int p = p0; p < p1; ++p) {
        int r = src[p];
        float nw = nrm[p];
        float4 hv = *(const float4*)(h + (size_t)r * HF + lane * 4);
        acc.x += nw * hv.x;
        acc.y += nw * hv.y;
        acc.z += nw * hv.z;
        acc.w += nw * hv.w;
    }
    // self loop: weight 1, norm = dinv^2
    float s = dinv[wid];
    float sl = s * s;
    float4 hv = *(const float4*)(h + (size_t)wid * HF + lane * 4);
    acc.x += sl * hv.x;
    acc.y += sl * hv.y;
    acc.z += sl * hv.z;
    acc.w += sl * hv.w;

    int f = lane * 4;
    float4 bb  = *(const float4*)(b + f);
    float4 gg  = *(const float4*)(g + f);
    float4 bee = *(const float4*)(be + f);
    float4 mm  = *(const float4*)(m + f);
    float4 vv  = *(const float4*)(v + f);
    float4 o;
    o.x = fmaxf((acc.x + bb.x - mm.x) * rsqrtf(vv.x + BN_EPS) * gg.x + bee.x, 0.f);
    o.y = fmaxf((acc.y + bb.y - mm.y) * rsqrtf(vv.y + BN_EPS) * gg.y + bee.y, 0.f);
    o.z = fmaxf((acc.z + bb.z - mm.z) * rsqrtf(vv.z + BN_EPS) * gg.z + bee.z, 0.f);
    o.w = fmaxf((acc.w + bb.w - mm.w) * rsqrtf(vv.w + BN_EPS) * gg.w + bee.w, 0.f);
    *(float4*)(out + (size_t)wid * HF + lane * 4) = o;
}

// ---------- layer 3 GEMV: h3[N,2] = a[N,256] @ W3[256,2] ----------
__global__ void gemv_out_kernel(const float* __restrict__ a, const float* __restrict__ W3,
                                float* __restrict__ h3, int n) {
    int gid = blockIdx.x * blockDim.x + threadIdx.x;
    int node = gid >> 6;
    int lane = gid & 63;
    if (node >= n) return;
    float4 av = *(const float4*)(a + (size_t)node * HF + lane * 4);
    int k = lane * 4;
    float acc0 = av.x * W3[(k + 0) * 2 + 0] + av.y * W3[(k + 1) * 2 + 0]
               + av.z * W3[(k + 2) * 2 + 0] + av.w * W3[(k + 3) * 2 + 0];
    float acc1 = av.x * W3[(k + 0) * 2 + 1] + av.y * W3[(k + 1) * 2 + 1]
               + av.z * W3[(k + 2) * 2 + 1] + av.w * W3[(k + 3) * 2 + 1];
    #pragma unroll
    for (int o = 32; o > 0; o >>= 1) {
        acc0 += __shfl_down(acc0, o, 64);
        acc1 += __shfl_down(acc1, o, 64);
    }
    if (lane == 0) {
        h3[node * 2 + 0] = acc0;
        h3[node * 2 + 1] = acc1;
    }
}

// ---------- final: CSR gather (2 features) + self-loop + bias ----------
__global__ void out_kernel(const float* __restrict__ h3,
                           const int* __restrict__ ptr, const int* __restrict__ src,
                           const float* __restrict__ nrm, const float* __restrict__ dinv,
                           const float* __restrict__ b3, float* __restrict__ out, int n) {
    int i = blockIdx.x * blockDim.x + threadIdx.x;
    if (i >= n) return;
    int p0 = ptr[i], p1 = ptr[i + 1];
    float a0 = 0.f, a1 = 0.f;
    for (int p = p0; p < p1; ++p) {
        int r = src[p];
        float nw = nrm[p];
        a0 += nw * h3[2 * r + 0];
        a1 += nw * h3[2 * r + 1];
    }
    float s = dinv[i];
    float sl = s * s;
    out[2 * i + 0] = a0 + sl * h3[2 * i + 0] + b3[0];
    out[2 * i + 1] = a1 + sl * h3[2 * i + 1] + b3[1];
}

extern "C" void kernel_launch(void* const* d_in, const int* in_sizes, int n_in,
                              void* d_out, int out_size, void* d_ws, size_t ws_size,
                              hipStream_t stream) {
    const float* x   = (const float*)d_in[0];
    const int*   ei  = (const int*)d_in[1];    // int64 in reference -> int32 in harness
    const float* ew  = (const float*)d_in[2];
    const float* W1  = (const float*)d_in[3];
    const float* b1  = (const float*)d_in[4];
    const float* g1  = (const float*)d_in[5];
    const float* be1 = (const float*)d_in[6];
    const float* m1  = (const float*)d_in[7];
    const float* v1  = (const float*)d_in[8];
    const float* W2  = (const float*)d_in[9];
    const float* b2  = (const float*)d_in[10];
    const float* g2  = (const float*)d_in[11];
    const float* be2 = (const float*)d_in[12];
    const float* m2  = (const float*)d_in[13];
    const float* v2  = (const float*)d_in[14];
    const float* W3  = (const float*)d_in[15];
    const float* b3  = (const float*)d_in[16];

    const int N = in_sizes[0] / F_IN;
    const int E = in_sizes[2];
    const int* row = ei;       // edge_index[0]
    const int* col = ei + E;   // edge_index[1]

    // workspace layout (all 4-byte elements)
    char* wsb = (char*)d_ws;
    float* dinv     = (float*)wsb;                      wsb += (size_t)N * 4;
    int*   hist     = (int*)wsb;                        wsb += (size_t)N * 4;
    int*   csr_ptr  = (int*)wsb;                        wsb += (size_t)(N + 1) * 4;
    int*   cursor   = (int*)wsb;                        wsb += (size_t)N * 4;
    int*   blocksum = (int*)wsb;                        wsb += (size_t)SCAN_B * 4;
    int*   csr_src  = (int*)wsb;                        wsb += (size_t)E * 4;
    float* csr_nrm  = (float*)wsb;                      wsb += (size_t)E * 4;
    float* buf1     = (float*)wsb;                      wsb += (size_t)N * HF * 4;
    float* buf2     = (float*)wsb;                      wsb += (size_t)N * HF * 4;
    float* h3       = (float*)wsb;                      wsb += (size_t)N * OUT_F * 4;
    float* outf = (float*)d_out;

    const int TB = 256;
    const int nscan = (N + SCAN_B - 1) / SCAN_B;       // 196 blocks for N=50000

    // --- graph preprocessing (once per launch; graph identical across layers) ---
    init_deg_kernel<<<(N + TB - 1) / TB, TB, 0, stream>>>(dinv, N);
    hipMemsetAsync(hist, 0, (size_t)N * sizeof(int), stream);
    count_deg_kernel<<<(E + TB - 1) / TB, TB, 0, stream>>>(col, ew, dinv, hist, E);
    dinv_kernel<<<(N + TB - 1) / TB, TB, 0, stream>>>(dinv, N);
    scan1_kernel<<<nscan, SCAN_B, 0, stream>>>(hist, csr_ptr, blocksum, N);
    scan2_kernel<<<1, SCAN_B, 0, stream>>>(blocksum, nscan);
    scan3_kernel<<<nscan, SCAN_B, 0, stream>>>(csr_ptr, cursor, blocksum, N, E);
    fill_kernel<<<(E + TB - 1) / TB, TB, 0, stream>>>(row, col, ew, dinv, cursor, csr_src, csr_nrm, E);

    dim3 gemm_grid((N + 63) / 64, HF / 64);

    // --- layer 1 ---
    sgemm_kernel<<<gemm_grid, TB, 0, stream>>>(x, W1, buf1, N, F_IN, HF);
    agg_bn_relu_kernel<<<((size_t)N * 64 + TB - 1) / TB, TB, 0, stream>>>(
        buf1, csr_ptr, csr_src, csr_nrm, dinv, b1, g1, be1, m1, v1, buf2, N);

    // --- layer 2 ---
    sgemm_kernel<<<gemm_grid, TB, 0, stream>>>(buf2, W2, buf1, N, HF, HF);
    agg_bn_relu_kernel<<<((size_t)N * 64 + TB - 1) / TB, TB, 0, stream>>>(
        buf1, csr_ptr, csr_src, csr_nrm, dinv, b2, g2, be2, m2, v2, buf2, N);

    // --- layer 3 ---
    gemv_out_kernel<<<((size_t)N * 64 + TB - 1) / TB, TB, 0, stream>>>(buf2, W3, h3, N);
    out_kernel<<<(N + TB - 1) / TB, TB, 0, stream>>>(h3, csr_ptr, csr_src, csr_nrm, dinv, b3, outf, N);
}

// Round 4
// 605.314 us; speedup vs baseline: 9.8629x; 1.4216x over previous
//
#include <hip/hip_runtime.h>
#include <stdint.h>

#define F_IN 512
#define HF 256
#define OUT_F 2
#define BN_EPS 1e-5f
#define SCAN_B 256

typedef __attribute__((ext_vector_type(8))) short bf16x8;
typedef __attribute__((ext_vector_type(4))) float f32x4;

__device__ inline float bf2f(unsigned short u) {
    union { float f; uint32_t i; } v; v.i = ((uint32_t)u) << 16; return v.f;
}
__device__ inline unsigned short f2bf(float f) {
    union { float f; uint32_t i; } v; v.f = f;
    uint32_t r = v.i + 0x7FFFu + ((v.i >> 16) & 1u);   // RNE (finite values only)
    return (unsigned short)(r >> 16);
}

// ---------- degree + histogram ----------
__global__ void init_deg_kernel(float* __restrict__ deg, int n) {
    int i = blockIdx.x * blockDim.x + threadIdx.x;
    if (i < n) deg[i] = 1.0f;   // self-loop weight
}

__global__ void count_deg_kernel(const int* __restrict__ col,
                                 const float* __restrict__ w,
                                 float* __restrict__ deg,
                                 int* __restrict__ hist, int e) {
    int i = blockIdx.x * blockDim.x + threadIdx.x;
    if (i < e) {
        int c = col[i];
        atomicAdd(&deg[c], w[i]);
        atomicAdd(&hist[c], 1);
    }
}

__global__ void dinv_kernel(float* __restrict__ deg, int n) {
    int i = blockIdx.x * blockDim.x + threadIdx.x;
    if (i < n) {
        float d = deg[i];
        deg[i] = d > 0.0f ? rsqrtf(d) : 0.0f;   // in-place: deg -> dinv
    }
}

// ---------- hierarchical exclusive scan (hist -> csr_ptr) ----------
__global__ void scan1_kernel(const int* __restrict__ hist, int* __restrict__ local,
                             int* __restrict__ blocksum, int n) {
    __shared__ int tmp[SCAN_B];
    int i = blockIdx.x * SCAN_B + threadIdx.x;
    int v = (i < n) ? hist[i] : 0;
    tmp[threadIdx.x] = v;
    __syncthreads();
    for (int off = 1; off < SCAN_B; off <<= 1) {
        int t = 0;
        if ((int)threadIdx.x >= off) t = tmp[threadIdx.x - off];
        __syncthreads();
        if ((int)threadIdx.x >= off) tmp[threadIdx.x] += t;
        __syncthreads();
    }
    if (i < n) local[i] = tmp[threadIdx.x] - v;       // exclusive
    if (threadIdx.x == SCAN_B - 1) blocksum[blockIdx.x] = tmp[SCAN_B - 1];
}

__global__ void scan2_kernel(int* __restrict__ blocksum, int nb) {
    __shared__ int tmp[SCAN_B];
    int v = ((int)threadIdx.x < nb) ? blocksum[threadIdx.x] : 0;
    tmp[threadIdx.x] = v;
    __syncthreads();
    for (int off = 1; off < SCAN_B; off <<= 1) {
        int t = 0;
        if ((int)threadIdx.x >= off) t = tmp[threadIdx.x - off];
        __syncthreads();
        if ((int)threadIdx.x >= off) tmp[threadIdx.x] += t;
        __syncthreads();
    }
    if ((int)threadIdx.x < nb) blocksum[threadIdx.x] = tmp[threadIdx.x] - v;   // exclusive
}

__global__ void scan3_kernel(int* __restrict__ csr_ptr, int* __restrict__ cursor,
                             const int* __restrict__ blocksum, int n, int e) {
    int i = blockIdx.x * SCAN_B + threadIdx.x;
    if (i < n) {
        int val = csr_ptr[i] + blocksum[blockIdx.x];
        csr_ptr[i] = val;
        cursor[i] = val;
    }
    if (i == 0) csr_ptr[n] = e;
}

// ---------- CSR fill: bucket edges by col, fold norm ----------
__global__ void fill_kernel(const int* __restrict__ row, const int* __restrict__ col,
                            const float* __restrict__ w, const float* __restrict__ dinv,
                            int* __restrict__ cursor, int* __restrict__ csr_src,
                            float* __restrict__ csr_norm, int e) {
    int i = blockIdx.x * blockDim.x + threadIdx.x;
    if (i < e) {
        int r = row[i], c = col[i];
        int pos = atomicAdd(&cursor[c], 1);
        csr_src[pos] = r;
        csr_norm[pos] = dinv[r] * w[i] * dinv[c];
    }
}

// ---------- W transpose + bf16 cast: Wt[n][k] = bf16(W[k][n]) ----------
__global__ void transpose_w_kernel(const float* __restrict__ W, unsigned short* __restrict__ Wt,
                                   int K, int Nt) {
    int idx = blockIdx.x * blockDim.x + threadIdx.x;   // k fastest -> coalesced writes
    if (idx < K * Nt) {
        int n = idx / K;
        int k = idx - n * K;
        Wt[idx] = f2bf(W[(size_t)k * Nt + n]);
    }
}

// ---------- bf16 MFMA GEMM: C[M,Ntot] = A[M,K] @ Bt[Ntot,K]^T ----------
// BM=128, BN=128, BK=32; 256 threads = 4 waves, each wave a 64x64 subtile
// (4x4 MFMA 16x16x32 tiles). A is fp32 (converted in staging) or bf16.
// C written as bf16. M rows beyond Mvalid read as zero (A guard); C rows
// are assumed padded to a multiple of 128 (no store guard).
template<int A_IS_F32>
__global__ __launch_bounds__(256)
void gemm_bf16_kernel(const void* __restrict__ Araw,
                      const unsigned short* __restrict__ Bt,
                      unsigned short* __restrict__ C,
                      int Mvalid, int K, int Ntot) {
    __shared__ unsigned short As[128 * 40];   // row stride 40 bf16 (pad: bank spread)
    __shared__ unsigned short Bs[128 * 40];
    const int tid  = threadIdx.x;
    const int lane = tid & 63;
    const int wv   = tid >> 6;
    const int wrow = wv >> 1, wcol = wv & 1;
    const int m0 = blockIdx.x * 128;
    const int n0 = blockIdx.y * 128;

    const int sr = tid >> 2;          // staging row 0..63
    const int sc = (tid & 3) * 8;     // staging k-offset 0,8,16,24

    f32x4 zero4 = {0.0f, 0.0f, 0.0f, 0.0f};
    f32x4 acc[4][4];
    #pragma unroll
    for (int i = 0; i < 4; ++i)
        #pragma unroll
        for (int j = 0; j < 4; ++j) acc[i][j] = zero4;

    const int q8 = (lane >> 4) * 8;   // k-offset of this lane's fragment
    const int ml = lane & 15;         // m (or n) within 16-tile

    for (int k0 = 0; k0 < K; k0 += 32) {
        // ---- stage A tile (128 x 32) ----
        if (A_IS_F32) {
            const float* A = (const float*)Araw;
            #pragma unroll
            for (int h = 0; h < 2; ++h) {
                int rr = sr + h * 64;
                int gm = m0 + rr;
                float4 f0 = {0.f, 0.f, 0.f, 0.f}, f1 = {0.f, 0.f, 0.f, 0.f};
                if (gm < Mvalid) {
                    f0 = *(const float4*)(A + (size_t)gm * K + k0 + sc);
                    f1 = *(const float4*)(A + (size_t)gm * K + k0 + sc + 4);
                }
                bf16x8 v;
                v[0] = (short)f2bf(f0.x); v[1] = (short)f2bf(f0.y);
                v[2] = (short)f2bf(f0.z); v[3] = (short)f2bf(f0.w);
                v[4] = (short)f2bf(f1.x); v[5] = (short)f2bf(f1.y);
                v[6] = (short)f2bf(f1.z); v[7] = (short)f2bf(f1.w);
                *(bf16x8*)&As[rr * 40 + sc] = v;
            }
        } else {
            const unsigned short* A = (const unsigned short*)Araw;
            #pragma unroll
            for (int h = 0; h < 2; ++h) {
                int rr = sr + h * 64;
                int gm = m0 + rr;
                bf16x8 v = {0, 0, 0, 0, 0, 0, 0, 0};
                if (gm < Mvalid) v = *(const bf16x8*)(A + (size_t)gm * K + k0 + sc);
                *(bf16x8*)&As[rr * 40 + sc] = v;
            }
        }
        // ---- stage B tile (128 n x 32 k) from Bt[Ntot][K] ----
        #pragma unroll
        for (int h = 0; h < 2; ++h) {
            int rr = sr + h * 64;
            bf16x8 v = *(const bf16x8*)(Bt + (size_t)(n0 + rr) * K + k0 + sc);
            *(bf16x8*)&Bs[rr * 40 + sc] = v;
        }
        __syncthreads();

        // ---- fragments + 16 MFMAs ----
        bf16x8 af[4], bfr[4];
        #pragma unroll
        for (int i = 0; i < 4; ++i)
            af[i] = *(const bf16x8*)&As[(wrow * 64 + i * 16 + ml) * 40 + q8];
        #pragma unroll
        for (int j = 0; j < 4; ++j)
            bfr[j] = *(const bf16x8*)&Bs[(wcol * 64 + j * 16 + ml) * 40 + q8];
        #pragma unroll
        for (int i = 0; i < 4; ++i)
            #pragma unroll
            for (int j = 0; j < 4; ++j)
                acc[i][j] = __builtin_amdgcn_mfma_f32_16x16x32_bf16(af[i], bfr[j], acc[i][j], 0, 0, 0);
        __syncthreads();
    }

    // ---- C store (bf16): col=lane&15, row=(lane>>4)*4+reg ----
    const int q4 = (lane >> 4) * 4;
    #pragma unroll
    for (int i = 0; i < 4; ++i) {
        #pragma unroll
        for (int j = 0; j < 4; ++j) {
            #pragma unroll
            for (int rg = 0; rg < 4; ++rg) {
                int r = m0 + wrow * 64 + i * 16 + q4 + rg;
                int c = n0 + wcol * 64 + j * 16 + ml;
                C[(size_t)r * Ntot + c] = f2bf(acc[i][j][rg]);
            }
        }
    }
}

// ---------- fused CSR gather + self-loop + bias + BN + ReLU (bf16 in/out) ----------
__global__ void agg_bn_relu_kernel(const unsigned short* __restrict__ h,
                                   const int* __restrict__ ptr,
                                   const int* __restrict__ src,
                                   const float* __restrict__ nrm,
                                   const float* __restrict__ dinv,
                                   const float* __restrict__ b, const float* __restrict__ g,
                                   const float* __restrict__ be, const float* __restrict__ m,
                                   const float* __restrict__ v,
                                   unsigned short* __restrict__ out, int n) {
    int wid  = (blockIdx.x * blockDim.x + threadIdx.x) >> 6;
    int lane = threadIdx.x & 63;
    if (wid >= n) return;
    int p0 = ptr[wid], p1 = ptr[wid + 1];
    const int fo = lane * 4;
    float a0 = 0.f, a1 = 0.f, a2 = 0.f, a3 = 0.f;
    for (int p = p0; p < p1; ++p) {
        int r = src[p];
        float nw = nrm[p];
        ushort4 hv = *(const ushort4*)(h + (size_t)r * HF + fo);
        a0 += nw * bf2f(hv.x);
        a1 += nw * bf2f(hv.y);
        a2 += nw * bf2f(hv.z);
        a3 += nw * bf2f(hv.w);
    }
    float s = dinv[wid];
    float sl = s * s;
    ushort4 hv = *(const ushort4*)(h + (size_t)wid * HF + fo);
    a0 += sl * bf2f(hv.x);
    a1 += sl * bf2f(hv.y);
    a2 += sl * bf2f(hv.z);
    a3 += sl * bf2f(hv.w);

    float4 bb  = *(const float4*)(b + fo);
    float4 gg  = *(const float4*)(g + fo);
    float4 bee = *(const float4*)(be + fo);
    float4 mm  = *(const float4*)(m + fo);
    float4 vv  = *(const float4*)(v + fo);
    ushort4 o;
    o.x = f2bf(fmaxf((a0 + bb.x - mm.x) * rsqrtf(vv.x + BN_EPS) * gg.x + bee.x, 0.f));
    o.y = f2bf(fmaxf((a1 + bb.y - mm.y) * rsqrtf(vv.y + BN_EPS) * gg.y + bee.y, 0.f));
    o.z = f2bf(fmaxf((a2 + bb.z - mm.z) * rsqrtf(vv.z + BN_EPS) * gg.z + bee.z, 0.f));
    o.w = f2bf(fmaxf((a3 + bb.w - mm.w) * rsqrtf(vv.w + BN_EPS) * gg.w + bee.w, 0.f));
    *(ushort4*)(out + (size_t)wid * HF + fo) = o;
}

// ---------- layer 3 GEMV: h3[N,2] = a[N,256](bf16) @ W3[256,2](fp32) ----------
__global__ void gemv_out_kernel(const unsigned short* __restrict__ a,
                                const float* __restrict__ W3,
                                float* __restrict__ h3, int n) {
    int gid = blockIdx.x * blockDim.x + threadIdx.x;
    int node = gid >> 6;
    int lane = gid & 63;
    if (node >= n) return;
    ushort4 av = *(const ushort4*)(a + (size_t)node * HF + lane * 4);
    float x0 = bf2f(av.x), x1 = bf2f(av.y), x2 = bf2f(av.z), x3 = bf2f(av.w);
    int k = lane * 4;
    float acc0 = x0 * W3[(k + 0) * 2 + 0] + x1 * W3[(k + 1) * 2 + 0]
               + x2 * W3[(k + 2) * 2 + 0] + x3 * W3[(k + 3) * 2 + 0];
    float acc1 = x0 * W3[(k + 0) * 2 + 1] + x1 * W3[(k + 1) * 2 + 1]
               + x2 * W3[(k + 2) * 2 + 1] + x3 * W3[(k + 3) * 2 + 1];
    #pragma unroll
    for (int o = 32; o > 0; o >>= 1) {
        acc0 += __shfl_down(acc0, o, 64);
        acc1 += __shfl_down(acc1, o, 64);
    }
    if (lane == 0) {
        h3[node * 2 + 0] = acc0;
        h3[node * 2 + 1] = acc1;
    }
}

// ---------- final: CSR gather (2 features) + self-loop + bias ----------
__global__ void out_kernel(const float* __restrict__ h3,
                           const int* __restrict__ ptr, const int* __restrict__ src,
                           const float* __restrict__ nrm, const float* __restrict__ dinv,
                           const float* __restrict__ b3, float* __restrict__ out, int n) {
    int i = blockIdx.x * blockDim.x + threadIdx.x;
    if (i >= n) return;
    int p0 = ptr[i], p1 = ptr[i + 1];
    float a0 = 0.f, a1 = 0.f;
    for (int p = p0; p < p1; ++p) {
        int r = src[p];
        float nw = nrm[p];
        a0 += nw * h3[2 * r + 0];
        a1 += nw * h3[2 * r + 1];
    }
    float s = dinv[i];
    float sl = s * s;
    out[2 * i + 0] = a0 + sl * h3[2 * i + 0] + b3[0];
    out[2 * i + 1] = a1 + sl * h3[2 * i + 1] + b3[1];
}

static inline char* align16(char* p) {
    return (char*)(((uintptr_t)p + 15) & ~(uintptr_t)15);
}

extern "C" void kernel_launch(void* const* d_in, const int* in_sizes, int n_in,
                              void* d_out, int out_size, void* d_ws, size_t ws_size,
                              hipStream_t stream) {
    const float* x   = (const float*)d_in[0];
    const int*   ei  = (const int*)d_in[1];    // int64 in reference -> int32 in harness
    const float* ew  = (const float*)d_in[2];
    const float* W1  = (const float*)d_in[3];
    const float* b1  = (const float*)d_in[4];
    const float* g1  = (const float*)d_in[5];
    const float* be1 = (const float*)d_in[6];
    const float* m1  = (const float*)d_in[7];
    const float* v1  = (const float*)d_in[8];
    const float* W2  = (const float*)d_in[9];
    const float* b2  = (const float*)d_in[10];
    const float* g2  = (const float*)d_in[11];
    const float* be2 = (const float*)d_in[12];
    const float* m2  = (const float*)d_in[13];
    const float* v2  = (const float*)d_in[14];
    const float* W3  = (const float*)d_in[15];
    const float* b3  = (const float*)d_in[16];

    const int N  = in_sizes[0] / F_IN;         // 50000
    const int E  = in_sizes[2];                // 800000
    const int MP = (N + 127) & ~127;           // 50048, multiple of 128
    const int* row = ei;
    const int* col = ei + E;

    // workspace layout (16B-aligned segments)
    char* wsb = (char*)d_ws;
    float* dinv     = (float*)wsb;          wsb = align16(wsb + (size_t)N * 4);
    int*   hist     = (int*)wsb;            wsb = align16(wsb + (size_t)N * 4);
    int*   csr_ptr  = (int*)wsb;            wsb = align16(wsb + (size_t)(N + 1) * 4);
    int*   cursor   = (int*)wsb;            wsb = align16(wsb + (size_t)N * 4);
    int*   blocksum = (int*)wsb;            wsb = align16(wsb + (size_t)SCAN_B * 4);
    int*   csr_src  = (int*)wsb;            wsb = align16(wsb + (size_t)E * 4);
    float* csr_nrm  = (float*)wsb;          wsb = align16(wsb + (size_t)E * 4);
    unsigned short* W1t = (unsigned short*)wsb;  wsb = align16(wsb + (size_t)F_IN * HF * 2);
    unsigned short* W2t = (unsigned short*)wsb;  wsb = align16(wsb + (size_t)HF * HF * 2);
    unsigned short* bufh = (unsigned short*)wsb; wsb = align16(wsb + (size_t)MP * HF * 2); // h1, then h2
    unsigned short* bufa = (unsigned short*)wsb; wsb = align16(wsb + (size_t)MP * HF * 2); // a1, then a2
    float* h3 = (float*)wsb;                wsb = align16(wsb + (size_t)N * OUT_F * 4);
    float* outf = (float*)d_out;

    const int TB = 256;
    const int nscan = (N + SCAN_B - 1) / SCAN_B;

    // --- graph preprocessing (graph identical across layers) ---
    init_deg_kernel<<<(N + TB - 1) / TB, TB, 0, stream>>>(dinv, N);
    hipMemsetAsync(hist, 0, (size_t)N * sizeof(int), stream);
    count_deg_kernel<<<(E + TB - 1) / TB, TB, 0, stream>>>(col, ew, dinv, hist, E);
    dinv_kernel<<<(N + TB - 1) / TB, TB, 0, stream>>>(dinv, N);
    scan1_kernel<<<nscan, SCAN_B, 0, stream>>>(hist, csr_ptr, blocksum, N);
    scan2_kernel<<<1, SCAN_B, 0, stream>>>(blocksum, nscan);
    scan3_kernel<<<nscan, SCAN_B, 0, stream>>>(csr_ptr, cursor, blocksum, N, E);
    fill_kernel<<<(E + TB - 1) / TB, TB, 0, stream>>>(row, col, ew, dinv, cursor, csr_src, csr_nrm, E);

    // --- weight prep (bf16 + transpose to [n][k]) ---
    transpose_w_kernel<<<(F_IN * HF + TB - 1) / TB, TB, 0, stream>>>(W1, W1t, F_IN, HF);
    transpose_w_kernel<<<(HF * HF + TB - 1) / TB, TB, 0, stream>>>(W2, W2t, HF, HF);
    // zero the pad rows of the activation buffer (they feed GEMM2 as A)
    hipMemsetAsync(bufa + (size_t)N * HF, 0, (size_t)(MP - N) * HF * 2, stream);

    dim3 ggrid(MP / 128, HF / 128);   // (391, 2)

    // --- layer 1: h1 = bf16(x) @ W1 ---
    gemm_bf16_kernel<1><<<ggrid, TB, 0, stream>>>(x, W1t, bufh, N, F_IN, HF);
    agg_bn_relu_kernel<<<((size_t)N * 64 + TB - 1) / TB, TB, 0, stream>>>(
        bufh, csr_ptr, csr_src, csr_nrm, dinv, b1, g1, be1, m1, v1, bufa, N);

    // --- layer 2: h2 = a1 @ W2 ---
    gemm_bf16_kernel<0><<<ggrid, TB, 0, stream>>>(bufa, W2t, bufh, MP, HF, HF);
    agg_bn_relu_kernel<<<((size_t)N * 64 + TB - 1) / TB, TB, 0, stream>>>(
        bufh, csr_ptr, csr_src, csr_nrm, dinv, b2, g2, be2, m2, v2, bufa, N);

    // --- layer 3 ---
    gemv_out_kernel<<<((size_t)N * 64 + TB - 1) / TB, TB, 0, stream>>>(bufa, W3, h3, N);
    out_kernel<<<(N + TB - 1) / TB, TB, 0, stream>>>(h3, csr_ptr, csr_src, csr_nrm, dinv, b3, outf, N);
}

// Round 5
// 544.550 us; speedup vs baseline: 10.9635x; 1.1116x over previous
//
#include <hip/hip_runtime.h>
#include <stdint.h>

#define F_IN 512
#define HF 256
#define OUT_F 2
#define BN_EPS 1e-5f
#define SCAN_B 256

typedef __attribute__((ext_vector_type(8))) short bf16x8;
typedef __attribute__((ext_vector_type(4))) float f32x4;

__device__ inline float bf2f(unsigned short u) {
    union { float f; uint32_t i; } v; v.i = ((uint32_t)u) << 16; return v.f;
}
__device__ inline unsigned short f2bf(float f) {
    union { float f; uint32_t i; } v; v.f = f;
    uint32_t r = v.i + 0x7FFFu + ((v.i >> 16) & 1u);   // RNE (finite values only)
    return (unsigned short)(r >> 16);
}

// ---------- init: deg=1 (self loop), hist=0 ----------
__global__ void init_kernel(float* __restrict__ deg, int* __restrict__ hist, int n) {
    int i = blockIdx.x * blockDim.x + threadIdx.x;
    if (i < n) { deg[i] = 1.0f; hist[i] = 0; }
}

__global__ void count_deg_kernel(const int* __restrict__ col,
                                 const float* __restrict__ w,
                                 float* __restrict__ deg,
                                 int* __restrict__ hist, int e) {
    int i = blockIdx.x * blockDim.x + threadIdx.x;
    if (i < e) {
        int c = col[i];
        atomicAdd(&deg[c], w[i]);
        atomicAdd(&hist[c], 1);
    }
}

// ---------- hierarchical exclusive scan (hist -> csr_ptr) ----------
__global__ void scan1_kernel(const int* __restrict__ hist, int* __restrict__ local,
                             int* __restrict__ blocksum, int n) {
    __shared__ int tmp[SCAN_B];
    int i = blockIdx.x * SCAN_B + threadIdx.x;
    int v = (i < n) ? hist[i] : 0;
    tmp[threadIdx.x] = v;
    __syncthreads();
    for (int off = 1; off < SCAN_B; off <<= 1) {
        int t = 0;
        if ((int)threadIdx.x >= off) t = tmp[threadIdx.x - off];
        __syncthreads();
        if ((int)threadIdx.x >= off) tmp[threadIdx.x] += t;
        __syncthreads();
    }
    if (i < n) local[i] = tmp[threadIdx.x] - v;       // exclusive
    if (threadIdx.x == SCAN_B - 1) blocksum[blockIdx.x] = tmp[SCAN_B - 1];
}

__global__ void scan2_kernel(int* __restrict__ blocksum, int nb) {
    __shared__ int tmp[SCAN_B];
    int v = ((int)threadIdx.x < nb) ? blocksum[threadIdx.x] : 0;
    tmp[threadIdx.x] = v;
    __syncthreads();
    for (int off = 1; off < SCAN_B; off <<= 1) {
        int t = 0;
        if ((int)threadIdx.x >= off) t = tmp[threadIdx.x - off];
        __syncthreads();
        if ((int)threadIdx.x >= off) tmp[threadIdx.x] += t;
        __syncthreads();
    }
    if ((int)threadIdx.x < nb) blocksum[threadIdx.x] = tmp[threadIdx.x] - v;   // exclusive
}

// scan3 + dinv fused (both per-node, dinv only needed by fill which runs after)
__global__ void scan3_dinv_kernel(int* __restrict__ csr_ptr, int* __restrict__ cursor,
                                  const int* __restrict__ blocksum,
                                  float* __restrict__ deg, int n, int e) {
    int i = blockIdx.x * SCAN_B + threadIdx.x;
    if (i < n) {
        int val = csr_ptr[i] + blocksum[blockIdx.x];
        csr_ptr[i] = val;
        cursor[i] = val;
        float d = deg[i];
        deg[i] = d > 0.0f ? rsqrtf(d) : 0.0f;   // in-place: deg -> dinv
    }
    if (i == 0) csr_ptr[n] = e;
}

// ---------- CSR fill: bucket edges by col, fold norm ----------
__global__ void fill_kernel(const int* __restrict__ row, const int* __restrict__ col,
                            const float* __restrict__ w, const float* __restrict__ dinv,
                            int* __restrict__ cursor, int* __restrict__ csr_src,
                            float* __restrict__ csr_norm, int e) {
    int i = blockIdx.x * blockDim.x + threadIdx.x;
    if (i < e) {
        int r = row[i], c = col[i];
        int pos = atomicAdd(&cursor[c], 1);
        csr_src[pos] = r;
        csr_norm[pos] = dinv[r] * w[i] * dinv[c];
    }
}

// ---------- both W transposes in one kernel: Wt[n][k] = bf16(W[k][n]) ----------
__global__ void transpose_w_kernel(const float* __restrict__ W1, unsigned short* __restrict__ W1t,
                                   const float* __restrict__ W2, unsigned short* __restrict__ W2t) {
    int idx = blockIdx.x * blockDim.x + threadIdx.x;
    if (idx < F_IN * HF) {                 // W1: K=F_IN, N=HF
        int n = idx / F_IN;
        int k = idx - n * F_IN;
        W1t[idx] = f2bf(W1[(size_t)k * HF + n]);
    } else if (idx < F_IN * HF + HF * HF) {  // W2: K=HF, N=HF
        int j = idx - F_IN * HF;
        int n = j / HF;
        int k = j - n * HF;
        W2t[j] = f2bf(W2[(size_t)k * HF + n]);
    }
}

// ---------- bf16 MFMA GEMM: C[M,Ntot] = A[M,K] @ Bt[Ntot,K]^T ----------
template<int A_IS_F32>
__global__ __launch_bounds__(256)
void gemm_bf16_kernel(const void* __restrict__ Araw,
                      const unsigned short* __restrict__ Bt,
                      unsigned short* __restrict__ C,
                      int Mvalid, int K, int Ntot) {
    __shared__ unsigned short As[128 * 40];   // row stride 40 bf16 (bank spread)
    __shared__ unsigned short Bs[128 * 40];
    const int tid  = threadIdx.x;
    const int lane = tid & 63;
    const int wv   = tid >> 6;
    const int wrow = wv >> 1, wcol = wv & 1;
    const int m0 = blockIdx.x * 128;
    const int n0 = blockIdx.y * 128;

    const int sr = tid >> 2;          // staging row 0..63
    const int sc = (tid & 3) * 8;     // staging k-offset 0,8,16,24

    f32x4 zero4 = {0.0f, 0.0f, 0.0f, 0.0f};
    f32x4 acc[4][4];
    #pragma unroll
    for (int i = 0; i < 4; ++i)
        #pragma unroll
        for (int j = 0; j < 4; ++j) acc[i][j] = zero4;

    const int q8 = (lane >> 4) * 8;
    const int ml = lane & 15;

    for (int k0 = 0; k0 < K; k0 += 32) {
        if (A_IS_F32) {
            const float* A = (const float*)Araw;
            #pragma unroll
            for (int h = 0; h < 2; ++h) {
                int rr = sr + h * 64;
                int gm = m0 + rr;
                float4 f0 = {0.f, 0.f, 0.f, 0.f}, f1 = {0.f, 0.f, 0.f, 0.f};
                if (gm < Mvalid) {
                    f0 = *(const float4*)(A + (size_t)gm * K + k0 + sc);
                    f1 = *(const float4*)(A + (size_t)gm * K + k0 + sc + 4);
                }
                bf16x8 v;
                v[0] = (short)f2bf(f0.x); v[1] = (short)f2bf(f0.y);
                v[2] = (short)f2bf(f0.z); v[3] = (short)f2bf(f0.w);
                v[4] = (short)f2bf(f1.x); v[5] = (short)f2bf(f1.y);
                v[6] = (short)f2bf(f1.z); v[7] = (short)f2bf(f1.w);
                *(bf16x8*)&As[rr * 40 + sc] = v;
            }
        } else {
            const unsigned short* A = (const unsigned short*)Araw;
            #pragma unroll
            for (int h = 0; h < 2; ++h) {
                int rr = sr + h * 64;
                int gm = m0 + rr;
                bf16x8 v = {0, 0, 0, 0, 0, 0, 0, 0};
                if (gm < Mvalid) v = *(const bf16x8*)(A + (size_t)gm * K + k0 + sc);
                *(bf16x8*)&As[rr * 40 + sc] = v;
            }
        }
        #pragma unroll
        for (int h = 0; h < 2; ++h) {
            int rr = sr + h * 64;
            bf16x8 v = *(const bf16x8*)(Bt + (size_t)(n0 + rr) * K + k0 + sc);
            *(bf16x8*)&Bs[rr * 40 + sc] = v;
        }
        __syncthreads();

        bf16x8 af[4], bfr[4];
        #pragma unroll
        for (int i = 0; i < 4; ++i)
            af[i] = *(const bf16x8*)&As[(wrow * 64 + i * 16 + ml) * 40 + q8];
        #pragma unroll
        for (int j = 0; j < 4; ++j)
            bfr[j] = *(const bf16x8*)&Bs[(wcol * 64 + j * 16 + ml) * 40 + q8];
        #pragma unroll
        for (int i = 0; i < 4; ++i)
            #pragma unroll
            for (int j = 0; j < 4; ++j)
                acc[i][j] = __builtin_amdgcn_mfma_f32_16x16x32_bf16(af[i], bfr[j], acc[i][j], 0, 0, 0);
        __syncthreads();
    }

    // C store (bf16): col=lane&15, row=(lane>>4)*4+reg
    const int q4 = (lane >> 4) * 4;
    #pragma unroll
    for (int i = 0; i < 4; ++i) {
        #pragma unroll
        for (int j = 0; j < 4; ++j) {
            #pragma unroll
            for (int rg = 0; rg < 4; ++rg) {
                int r = m0 + wrow * 64 + i * 16 + q4 + rg;
                int c = n0 + wcol * 64 + j * 16 + ml;
                C[(size_t)r * Ntot + c] = f2bf(acc[i][j][rg]);
            }
        }
    }
}

// ---------- fused CSR gather + self-loop + bias + BN + ReLU (bf16 in/out) ----------
// one wave per node; edge loop unrolled x4 -> 4 independent row-gathers in flight
__global__ void agg_bn_relu_kernel(const unsigned short* __restrict__ h,
                                   const int* __restrict__ ptr,
                                   const int* __restrict__ src,
                                   const float* __restrict__ nrm,
                                   const float* __restrict__ dinv,
                                   const float* __restrict__ b, const float* __restrict__ g,
                                   const float* __restrict__ be, const float* __restrict__ m,
                                   const float* __restrict__ v,
                                   unsigned short* __restrict__ out, int n) {
    int wid  = (blockIdx.x * blockDim.x + threadIdx.x) >> 6;
    int lane = threadIdx.x & 63;
    if (wid >= n) return;
    int p0 = ptr[wid], p1 = ptr[wid + 1];
    const int fo = lane * 4;
    float a0 = 0.f, a1 = 0.f, a2 = 0.f, a3 = 0.f;

    int p = p0;
    for (; p + 4 <= p1; p += 4) {
        int r0 = src[p], r1 = src[p + 1], r2 = src[p + 2], r3 = src[p + 3];
        float w0 = nrm[p], w1 = nrm[p + 1], w2 = nrm[p + 2], w3 = nrm[p + 3];
        ushort4 v0 = *(const ushort4*)(h + (size_t)r0 * HF + fo);
        ushort4 v1 = *(const ushort4*)(h + (size_t)r1 * HF + fo);
        ushort4 v2 = *(const ushort4*)(h + (size_t)r2 * HF + fo);
        ushort4 v3 = *(const ushort4*)(h + (size_t)r3 * HF + fo);
        a0 += w0 * bf2f(v0.x) + w1 * bf2f(v1.x) + w2 * bf2f(v2.x) + w3 * bf2f(v3.x);
        a1 += w0 * bf2f(v0.y) + w1 * bf2f(v1.y) + w2 * bf2f(v2.y) + w3 * bf2f(v3.y);
        a2 += w0 * bf2f(v0.z) + w1 * bf2f(v1.z) + w2 * bf2f(v2.z) + w3 * bf2f(v3.z);
        a3 += w0 * bf2f(v0.w) + w1 * bf2f(v1.w) + w2 * bf2f(v2.w) + w3 * bf2f(v3.w);
    }
    for (; p < p1; ++p) {
        int r = src[p];
        float nw = nrm[p];
        ushort4 hv = *(const ushort4*)(h + (size_t)r * HF + fo);
        a0 += nw * bf2f(hv.x);
        a1 += nw * bf2f(hv.y);
        a2 += nw * bf2f(hv.z);
        a3 += nw * bf2f(hv.w);
    }
    // self loop: weight 1, norm = dinv^2
    float s = dinv[wid];
    float sl = s * s;
    ushort4 hv = *(const ushort4*)(h + (size_t)wid * HF + fo);
    a0 += sl * bf2f(hv.x);
    a1 += sl * bf2f(hv.y);
    a2 += sl * bf2f(hv.z);
    a3 += sl * bf2f(hv.w);

    float4 bb  = *(const float4*)(b + fo);
    float4 gg  = *(const float4*)(g + fo);
    float4 bee = *(const float4*)(be + fo);
    float4 mm  = *(const float4*)(m + fo);
    float4 vv  = *(const float4*)(v + fo);
    ushort4 o;
    o.x = f2bf(fmaxf((a0 + bb.x - mm.x) * rsqrtf(vv.x + BN_EPS) * gg.x + bee.x, 0.f));
    o.y = f2bf(fmaxf((a1 + bb.y - mm.y) * rsqrtf(vv.y + BN_EPS) * gg.y + bee.y, 0.f));
    o.z = f2bf(fmaxf((a2 + bb.z - mm.z) * rsqrtf(vv.z + BN_EPS) * gg.z + bee.z, 0.f));
    o.w = f2bf(fmaxf((a3 + bb.w - mm.w) * rsqrtf(vv.w + BN_EPS) * gg.w + bee.w, 0.f));
    *(ushort4*)(out + (size_t)wid * HF + fo) = o;
}

// ---------- layer 3 GEMV: h3[N,2] = a[N,256](bf16) @ W3[256,2](fp32) ----------
__global__ void gemv_out_kernel(const unsigned short* __restrict__ a,
                                const float* __restrict__ W3,
                                float* __restrict__ h3, int n) {
    int gid = blockIdx.x * blockDim.x + threadIdx.x;
    int node = gid >> 6;
    int lane = gid & 63;
    if (node >= n) return;
    ushort4 av = *(const ushort4*)(a + (size_t)node * HF + lane * 4);
    float x0 = bf2f(av.x), x1 = bf2f(av.y), x2 = bf2f(av.z), x3 = bf2f(av.w);
    int k = lane * 4;
    float acc0 = x0 * W3[(k + 0) * 2 + 0] + x1 * W3[(k + 1) * 2 + 0]
               + x2 * W3[(k + 2) * 2 + 0] + x3 * W3[(k + 3) * 2 + 0];
    float acc1 = x0 * W3[(k + 0) * 2 + 1] + x1 * W3[(k + 1) * 2 + 1]
               + x2 * W3[(k + 2) * 2 + 1] + x3 * W3[(k + 3) * 2 + 1];
    #pragma unroll
    for (int o = 32; o > 0; o >>= 1) {
        acc0 += __shfl_down(acc0, o, 64);
        acc1 += __shfl_down(acc1, o, 64);
    }
    if (lane == 0) {
        h3[node * 2 + 0] = acc0;
        h3[node * 2 + 1] = acc1;
    }
}

// ---------- final: CSR gather (2 features) + self-loop + bias ----------
__global__ void out_kernel(const float* __restrict__ h3,
                           const int* __restrict__ ptr, const int* __restrict__ src,
                           const float* __restrict__ nrm, const float* __restrict__ dinv,
                           const float* __restrict__ b3, float* __restrict__ out, int n) {
    int i = blockIdx.x * blockDim.x + threadIdx.x;
    if (i >= n) return;
    int p0 = ptr[i], p1 = ptr[i + 1];
    float a0 = 0.f, a1 = 0.f;
    int p = p0;
    for (; p + 2 <= p1; p += 2) {
        int r0 = src[p], r1 = src[p + 1];
        float w0 = nrm[p], w1 = nrm[p + 1];
        float2 u0 = *(const float2*)(h3 + 2 * r0);
        float2 u1 = *(const float2*)(h3 + 2 * r1);
        a0 += w0 * u0.x + w1 * u1.x;
        a1 += w0 * u0.y + w1 * u1.y;
    }
    for (; p < p1; ++p) {
        int r = src[p];
        float nw = nrm[p];
        a0 += nw * h3[2 * r + 0];
        a1 += nw * h3[2 * r + 1];
    }
    float s = dinv[i];
    float sl = s * s;
    out[2 * i + 0] = a0 + sl * h3[2 * i + 0] + b3[0];
    out[2 * i + 1] = a1 + sl * h3[2 * i + 1] + b3[1];
}

static inline char* align16(char* p) {
    return (char*)(((uintptr_t)p + 15) & ~(uintptr_t)15);
}

extern "C" void kernel_launch(void* const* d_in, const int* in_sizes, int n_in,
                              void* d_out, int out_size, void* d_ws, size_t ws_size,
                              hipStream_t stream) {
    const float* x   = (const float*)d_in[0];
    const int*   ei  = (const int*)d_in[1];    // int64 in reference -> int32 in harness
    const float* ew  = (const float*)d_in[2];
    const float* W1  = (const float*)d_in[3];
    const float* b1  = (const float*)d_in[4];
    const float* g1  = (const float*)d_in[5];
    const float* be1 = (const float*)d_in[6];
    const float* m1  = (const float*)d_in[7];
    const float* v1  = (const float*)d_in[8];
    const float* W2  = (const float*)d_in[9];
    const float* b2  = (const float*)d_in[10];
    const float* g2  = (const float*)d_in[11];
    const float* be2 = (const float*)d_in[12];
    const float* m2  = (const float*)d_in[13];
    const float* v2  = (const float*)d_in[14];
    const float* W3  = (const float*)d_in[15];
    const float* b3  = (const float*)d_in[16];

    const int N  = in_sizes[0] / F_IN;         // 50000
    const int E  = in_sizes[2];                // 800000
    const int MP = (N + 127) & ~127;           // 50048
    const int* row = ei;
    const int* col = ei + E;

    char* wsb = (char*)d_ws;
    float* dinv     = (float*)wsb;          wsb = align16(wsb + (size_t)N * 4);
    int*   hist     = (int*)wsb;            wsb = align16(wsb + (size_t)N * 4);
    int*   csr_ptr  = (int*)wsb;            wsb = align16(wsb + (size_t)(N + 1) * 4);
    int*   cursor   = (int*)wsb;            wsb = align16(wsb + (size_t)N * 4);
    int*   blocksum = (int*)wsb;            wsb = align16(wsb + (size_t)SCAN_B * 4);
    int*   csr_src  = (int*)wsb;            wsb = align16(wsb + (size_t)E * 4);
    float* csr_nrm  = (float*)wsb;          wsb = align16(wsb + (size_t)E * 4);
    unsigned short* W1t = (unsigned short*)wsb;  wsb = align16(wsb + (size_t)F_IN * HF * 2);
    unsigned short* W2t = (unsigned short*)wsb;  wsb = align16(wsb + (size_t)HF * HF * 2);
    unsigned short* bufh = (unsigned short*)wsb; wsb = align16(wsb + (size_t)MP * HF * 2);
    unsigned short* bufa = (unsigned short*)wsb; wsb = align16(wsb + (size_t)MP * HF * 2);
    float* h3 = (float*)wsb;                wsb = align16(wsb + (size_t)N * OUT_F * 4);
    float* outf = (float*)d_out;

    const int TB = 256;
    const int nscan = (N + SCAN_B - 1) / SCAN_B;

    // --- graph preprocessing (graph identical across all 3 layers) ---
    init_kernel<<<(N + TB - 1) / TB, TB, 0, stream>>>(dinv, hist, N);
    count_deg_kernel<<<(E + TB - 1) / TB, TB, 0, stream>>>(col, ew, dinv, hist, E);
    scan1_kernel<<<nscan, SCAN_B, 0, stream>>>(hist, csr_ptr, blocksum, N);
    scan2_kernel<<<1, SCAN_B, 0, stream>>>(blocksum, nscan);
    scan3_dinv_kernel<<<nscan, SCAN_B, 0, stream>>>(csr_ptr, cursor, blocksum, dinv, N, E);
    fill_kernel<<<(E + TB - 1) / TB, TB, 0, stream>>>(row, col, ew, dinv, cursor, csr_src, csr_nrm, E);

    // --- weight prep + pad-row zero ---
    transpose_w_kernel<<<(F_IN * HF + HF * HF + TB - 1) / TB, TB, 0, stream>>>(W1, W1t, W2, W2t);
    hipMemsetAsync(bufa + (size_t)N * HF, 0, (size_t)(MP - N) * HF * 2, stream);

    dim3 ggrid(MP / 128, HF / 128);

    // --- layer 1 ---
    gemm_bf16_kernel<1><<<ggrid, TB, 0, stream>>>(x, W1t, bufh, N, F_IN, HF);
    agg_bn_relu_kernel<<<((size_t)N * 64 + TB - 1) / TB, TB, 0, stream>>>(
        bufh, csr_ptr, csr_src, csr_nrm, dinv, b1, g1, be1, m1, v1, bufa, N);

    // --- layer 2 ---
    gemm_bf16_kernel<0><<<ggrid, TB, 0, stream>>>(bufa, W2t, bufh, MP, HF, HF);
    agg_bn_relu_kernel<<<((size_t)N * 64 + TB - 1) / TB, TB, 0, stream>>>(
        bufh, csr_ptr, csr_src, csr_nrm, dinv, b2, g2, be2, m2, v2, bufa, N);

    // --- layer 3 ---
    gemv_out_kernel<<<((size_t)N * 64 + TB - 1) / TB, TB, 0, stream>>>(bufa, W3, h3, N);
    out_kernel<<<(N + TB - 1) / TB, TB, 0, stream>>>(h3, csr_ptr, csr_src, csr_nrm, dinv, b3, outf, N);
}

// Round 6
// 523.450 us; speedup vs baseline: 11.4054x; 1.0403x over previous
//
#include <hip/hip_runtime.h>
#include <stdint.h>

#define F_IN 512
#define HF 256
#define OUT_F 2
#define BN_EPS 1e-5f
#define SCAN_B 256

typedef __attribute__((ext_vector_type(8))) short bf16x8;
typedef __attribute__((ext_vector_type(4))) float f32x4;

__device__ inline float bf2f(unsigned short u) {
    union { float f; uint32_t i; } v; v.i = ((uint32_t)u) << 16; return v.f;
}
__device__ inline unsigned short f2bf(float f) {
    union { float f; uint32_t i; } v; v.f = f;
    uint32_t r = v.i + 0x7FFFu + ((v.i >> 16) & 1u);   // RNE (finite values only)
    return (unsigned short)(r >> 16);
}

// ---------- prep: packed init + W1/W2 transpose-to-bf16 + pad-row zero ----------
// packed[c] accumulates (count<<40) | fixpoint20(sum w). init = self-loop w=1.0.
__global__ void prep_kernel(unsigned long long* __restrict__ packed,
                            const float* __restrict__ W1, unsigned short* __restrict__ W1t,
                            const float* __restrict__ W2, unsigned short* __restrict__ W2t,
                            unsigned short* __restrict__ pad, int n, int padcount) {
    int idx = blockIdx.x * blockDim.x + threadIdx.x;
    if (idx < n) { packed[idx] = 1ULL << 20; return; }
    int j = idx - n;
    if (j < F_IN * HF) {                       // W1t[nn*F_IN + k] = bf16(W1[k*HF + nn])
        int nn = j >> 9, k = j & (F_IN - 1);
        W1t[j] = f2bf(W1[(size_t)k * HF + nn]);
        return;
    }
    j -= F_IN * HF;
    if (j < HF * HF) {                         // W2t[nn*HF + k] = bf16(W2[k*HF + nn])
        int nn = j >> 8, k = j & (HF - 1);
        W2t[j] = f2bf(W2[(size_t)k * HF + nn]);
        return;
    }
    j -= HF * HF;
    if (j < padcount) pad[j] = 0;
}

// ---------- one packed 64-bit atomic per edge: deg-sum + count ----------
__global__ void count_pack_kernel(const int* __restrict__ col,
                                  const float* __restrict__ w,
                                  unsigned long long* __restrict__ packed, int e) {
    int i = blockIdx.x * blockDim.x + threadIdx.x;
    if (i < e) {
        unsigned long long add = (1ULL << 40)
            | (unsigned long long)__float2uint_rn(w[i] * 1048576.0f);
        atomicAdd(&packed[col[i]], add);
    }
}

// ---------- scan1: block-local exclusive scan of counts ----------
__global__ void scan1_kernel(const unsigned long long* __restrict__ packed,
                             int* __restrict__ local, int* __restrict__ blocksum, int n) {
    __shared__ int tmp[SCAN_B];
    int i = blockIdx.x * SCAN_B + threadIdx.x;
    int v = (i < n) ? (int)(packed[i] >> 40) : 0;
    tmp[threadIdx.x] = v;
    __syncthreads();
    for (int off = 1; off < SCAN_B; off <<= 1) {
        int t = 0;
        if ((int)threadIdx.x >= off) t = tmp[threadIdx.x - off];
        __syncthreads();
        if ((int)threadIdx.x >= off) tmp[threadIdx.x] += t;
        __syncthreads();
    }
    if (i < n) local[i] = tmp[threadIdx.x] - v;       // exclusive
    if (threadIdx.x == SCAN_B - 1) blocksum[blockIdx.x] = tmp[SCAN_B - 1];
}

// ---------- scan3: add block prefix (re-reduced in-block) + dinv from packed ----------
__global__ void scan3_dinv_kernel(int* __restrict__ csr_ptr, int* __restrict__ cursor,
                                  const int* __restrict__ blocksum,
                                  const unsigned long long* __restrict__ packed,
                                  float* __restrict__ dinv, int n, int e, int nb) {
    __shared__ int red[SCAN_B];
    int t = threadIdx.x;
    red[t] = (t < nb && t < (int)blockIdx.x) ? blocksum[t] : 0;
    __syncthreads();
    for (int off = SCAN_B / 2; off > 0; off >>= 1) {
        if (t < off) red[t] += red[t + off];
        __syncthreads();
    }
    int prefix = red[0];
    int i = blockIdx.x * SCAN_B + t;
    if (i < n) {
        int val = csr_ptr[i] + prefix;
        csr_ptr[i] = val;
        cursor[i] = val;
        unsigned long long pk = packed[i];
        float deg = (float)(pk & 0xFFFFFFFFFFULL) * (1.0f / 1048576.0f);  // includes self-loop 1.0
        dinv[i] = rsqrtf(deg);   // deg >= 1 always
    }
    if (i == 0) csr_ptr[n] = e;
}

// ---------- CSR fill: bucket edges by col, fold norm, 8B paired store ----------
__global__ void fill_kernel(const int* __restrict__ row, const int* __restrict__ col,
                            const float* __restrict__ w, const float* __restrict__ dinv,
                            int* __restrict__ cursor, int2* __restrict__ csr_edge, int e) {
    int i = blockIdx.x * blockDim.x + threadIdx.x;
    if (i < e) {
        int r = row[i], c = col[i];
        int pos = atomicAdd(&cursor[c], 1);
        float nrm = dinv[r] * w[i] * dinv[c];
        csr_edge[pos] = make_int2(r, __float_as_int(nrm));
    }
}

// ---------- bf16 MFMA GEMM: C[M,Ntot] = A[M,K] @ Bt[Ntot,K]^T ----------
// BM=128, BN=64, BK=32; 256 threads = 4 waves; wave w: rows w*32..+32, cols 0..64
// (2x4 MFMA 16x16x32 tiles). Grid x covers M/128 (M padded), y covers Ntot/64.
template<int A_IS_F32>
__global__ __launch_bounds__(256)
void gemm_bf16_kernel(const void* __restrict__ Araw,
                      const unsigned short* __restrict__ Bt,
                      unsigned short* __restrict__ C,
                      int Mvalid, int K, int Ntot) {
    __shared__ unsigned short As[128 * 40];   // row stride 40 bf16 (bank spread)
    __shared__ unsigned short Bs[64 * 40];
    const int tid  = threadIdx.x;
    const int lane = tid & 63;
    const int wv   = tid >> 6;
    const int m0 = blockIdx.x * 128;
    const int n0 = blockIdx.y * 64;

    const int sr = tid >> 2;          // staging row 0..63
    const int sc = (tid & 3) * 8;     // staging k-offset 0,8,16,24

    f32x4 zero4 = {0.0f, 0.0f, 0.0f, 0.0f};
    f32x4 acc[2][4];
    #pragma unroll
    for (int i = 0; i < 2; ++i)
        #pragma unroll
        for (int j = 0; j < 4; ++j) acc[i][j] = zero4;

    const int q8 = (lane >> 4) * 8;
    const int ml = lane & 15;

    for (int k0 = 0; k0 < K; k0 += 32) {
        if (A_IS_F32) {
            const float* A = (const float*)Araw;
            #pragma unroll
            for (int h = 0; h < 2; ++h) {
                int rr = sr + h * 64;
                int gm = m0 + rr;
                float4 f0 = {0.f, 0.f, 0.f, 0.f}, f1 = {0.f, 0.f, 0.f, 0.f};
                if (gm < Mvalid) {
                    f0 = *(const float4*)(A + (size_t)gm * K + k0 + sc);
                    f1 = *(const float4*)(A + (size_t)gm * K + k0 + sc + 4);
                }
                bf16x8 v;
                v[0] = (short)f2bf(f0.x); v[1] = (short)f2bf(f0.y);
                v[2] = (short)f2bf(f0.z); v[3] = (short)f2bf(f0.w);
                v[4] = (short)f2bf(f1.x); v[5] = (short)f2bf(f1.y);
                v[6] = (short)f2bf(f1.z); v[7] = (short)f2bf(f1.w);
                *(bf16x8*)&As[rr * 40 + sc] = v;
            }
        } else {
            const unsigned short* A = (const unsigned short*)Araw;
            #pragma unroll
            for (int h = 0; h < 2; ++h) {
                int rr = sr + h * 64;
                int gm = m0 + rr;
                bf16x8 v = {0, 0, 0, 0, 0, 0, 0, 0};
                if (gm < Mvalid) v = *(const bf16x8*)(A + (size_t)gm * K + k0 + sc);
                *(bf16x8*)&As[rr * 40 + sc] = v;
            }
        }
        {   // B tile: 64 rows x 32 k
            bf16x8 v = *(const bf16x8*)(Bt + (size_t)(n0 + sr) * K + k0 + sc);
            *(bf16x8*)&Bs[sr * 40 + sc] = v;
        }
        __syncthreads();

        bf16x8 af[2], bfr[4];
        #pragma unroll
        for (int i = 0; i < 2; ++i)
            af[i] = *(const bf16x8*)&As[(wv * 32 + i * 16 + ml) * 40 + q8];
        #pragma unroll
        for (int j = 0; j < 4; ++j)
            bfr[j] = *(const bf16x8*)&Bs[(j * 16 + ml) * 40 + q8];
        #pragma unroll
        for (int i = 0; i < 2; ++i)
            #pragma unroll
            for (int j = 0; j < 4; ++j)
                acc[i][j] = __builtin_amdgcn_mfma_f32_16x16x32_bf16(af[i], bfr[j], acc[i][j], 0, 0, 0);
        __syncthreads();
    }

    // C store (bf16): col=lane&15, row=(lane>>4)*4+reg
    const int q4 = (lane >> 4) * 4;
    #pragma unroll
    for (int i = 0; i < 2; ++i) {
        #pragma unroll
        for (int j = 0; j < 4; ++j) {
            #pragma unroll
            for (int rg = 0; rg < 4; ++rg) {
                int r = m0 + wv * 32 + i * 16 + q4 + rg;
                int c = n0 + j * 16 + ml;
                C[(size_t)r * Ntot + c] = f2bf(acc[i][j][rg]);
            }
        }
    }
}

// ---------- fused CSR gather + self-loop + bias + BN + ReLU (bf16 in/out) ----------
// one wave per node; guarded batches of 8 -> 8 independent gathers always in flight
__global__ void agg_bn_relu_kernel(const unsigned short* __restrict__ h,
                                   const int* __restrict__ ptr,
                                   const int2* __restrict__ edge,
                                   const float* __restrict__ dinv,
                                   const float* __restrict__ b, const float* __restrict__ g,
                                   const float* __restrict__ be, const float* __restrict__ m,
                                   const float* __restrict__ v,
                                   unsigned short* __restrict__ out, int n) {
    int wid  = (blockIdx.x * blockDim.x + threadIdx.x) >> 6;
    int lane = threadIdx.x & 63;
    if (wid >= n) return;
    int p0 = ptr[wid], p1 = ptr[wid + 1];
    const int fo = lane * 4;
    float a0 = 0.f, a1 = 0.f, a2 = 0.f, a3 = 0.f;

    for (int p = p0; p < p1; p += 8) {
        int   rr[8];
        float ww[8];
        #pragma unroll
        for (int k = 0; k < 8; ++k) {
            bool valid = (p + k) < p1;
            int2 e = edge[valid ? p + k : p0];
            rr[k] = e.x;
            ww[k] = valid ? __int_as_float(e.y) : 0.0f;
        }
        ushort4 hv[8];
        #pragma unroll
        for (int k = 0; k < 8; ++k)
            hv[k] = *(const ushort4*)(h + (size_t)rr[k] * HF + fo);
        #pragma unroll
        for (int k = 0; k < 8; ++k) {
            a0 += ww[k] * bf2f(hv[k].x);
            a1 += ww[k] * bf2f(hv[k].y);
            a2 += ww[k] * bf2f(hv[k].z);
            a3 += ww[k] * bf2f(hv[k].w);
        }
    }
    // self loop: weight 1, norm = dinv^2
    float s = dinv[wid];
    float sl = s * s;
    ushort4 hv = *(const ushort4*)(h + (size_t)wid * HF + fo);
    a0 += sl * bf2f(hv.x);
    a1 += sl * bf2f(hv.y);
    a2 += sl * bf2f(hv.z);
    a3 += sl * bf2f(hv.w);

    float4 bb  = *(const float4*)(b + fo);
    float4 gg  = *(const float4*)(g + fo);
    float4 bee = *(const float4*)(be + fo);
    float4 mm  = *(const float4*)(m + fo);
    float4 vv  = *(const float4*)(v + fo);
    ushort4 o;
    o.x = f2bf(fmaxf((a0 + bb.x - mm.x) * rsqrtf(vv.x + BN_EPS) * gg.x + bee.x, 0.f));
    o.y = f2bf(fmaxf((a1 + bb.y - mm.y) * rsqrtf(vv.y + BN_EPS) * gg.y + bee.y, 0.f));
    o.z = f2bf(fmaxf((a2 + bb.z - mm.z) * rsqrtf(vv.z + BN_EPS) * gg.z + bee.z, 0.f));
    o.w = f2bf(fmaxf((a3 + bb.w - mm.w) * rsqrtf(vv.w + BN_EPS) * gg.w + bee.w, 0.f));
    *(ushort4*)(out + (size_t)wid * HF + fo) = o;
}

// ---------- layer 3 GEMV: h3[N,2] = a[N,256](bf16) @ W3[256,2](fp32) ----------
__global__ void gemv_out_kernel(const unsigned short* __restrict__ a,
                                const float* __restrict__ W3,
                                float* __restrict__ h3, int n) {
    int gid = blockIdx.x * blockDim.x + threadIdx.x;
    int node = gid >> 6;
    int lane = gid & 63;
    if (node >= n) return;
    ushort4 av = *(const ushort4*)(a + (size_t)node * HF + lane * 4);
    float x0 = bf2f(av.x), x1 = bf2f(av.y), x2 = bf2f(av.z), x3 = bf2f(av.w);
    int k = lane * 4;
    float acc0 = x0 * W3[(k + 0) * 2 + 0] + x1 * W3[(k + 1) * 2 + 0]
               + x2 * W3[(k + 2) * 2 + 0] + x3 * W3[(k + 3) * 2 + 0];
    float acc1 = x0 * W3[(k + 0) * 2 + 1] + x1 * W3[(k + 1) * 2 + 1]
               + x2 * W3[(k + 2) * 2 + 1] + x3 * W3[(k + 3) * 2 + 1];
    #pragma unroll
    for (int o = 32; o > 0; o >>= 1) {
        acc0 += __shfl_down(acc0, o, 64);
        acc1 += __shfl_down(acc1, o, 64);
    }
    if (lane == 0) {
        h3[node * 2 + 0] = acc0;
        h3[node * 2 + 1] = acc1;
    }
}

// ---------- final: CSR gather (2 features) + self-loop + bias ----------
__global__ void out_kernel(const float* __restrict__ h3,
                           const int* __restrict__ ptr, const int2* __restrict__ edge,
                           const float* __restrict__ dinv,
                           const float* __restrict__ b3, float* __restrict__ out, int n) {
    int i = blockIdx.x * blockDim.x + threadIdx.x;
    if (i >= n) return;
    int p0 = ptr[i], p1 = ptr[i + 1];
    float a0 = 0.f, a1 = 0.f;
    for (int p = p0; p < p1; p += 4) {
        #pragma unroll
        for (int k = 0; k < 4; ++k) {
            bool valid = (p + k) < p1;
            int2 e = edge[valid ? p + k : p0];
            float nw = valid ? __int_as_float(e.y) : 0.0f;
            float2 u = *(const float2*)(h3 + 2 * e.x);
            a0 += nw * u.x;
            a1 += nw * u.y;
        }
    }
    float s = dinv[i];
    float sl = s * s;
    out[2 * i + 0] = a0 + sl * h3[2 * i + 0] + b3[0];
    out[2 * i + 1] = a1 + sl * h3[2 * i + 1] + b3[1];
}

static inline char* align16(char* p) {
    return (char*)(((uintptr_t)p + 15) & ~(uintptr_t)15);
}

extern "C" void kernel_launch(void* const* d_in, const int* in_sizes, int n_in,
                              void* d_out, int out_size, void* d_ws, size_t ws_size,
                              hipStream_t stream) {
    const float* x   = (const float*)d_in[0];
    const int*   ei  = (const int*)d_in[1];    // int64 in reference -> int32 in harness
    const float* ew  = (const float*)d_in[2];
    const float* W1  = (const float*)d_in[3];
    const float* b1  = (const float*)d_in[4];
    const float* g1  = (const float*)d_in[5];
    const float* be1 = (const float*)d_in[6];
    const float* m1  = (const float*)d_in[7];
    const float* v1  = (const float*)d_in[8];
    const float* W2  = (const float*)d_in[9];
    const float* b2  = (const float*)d_in[10];
    const float* g2  = (const float*)d_in[11];
    const float* be2 = (const float*)d_in[12];
    const float* m2  = (const float*)d_in[13];
    const float* v2  = (const float*)d_in[14];
    const float* W3  = (const float*)d_in[15];
    const float* b3  = (const float*)d_in[16];

    const int N  = in_sizes[0] / F_IN;         // 50000
    const int E  = in_sizes[2];                // 800000
    const int MP = (N + 127) & ~127;           // 50048
    const int* row = ei;
    const int* col = ei + E;

    char* wsb = (char*)d_ws;
    unsigned long long* packed = (unsigned long long*)wsb; wsb = align16(wsb + (size_t)N * 8);
    float* dinv     = (float*)wsb;          wsb = align16(wsb + (size_t)N * 4);
    int*   csr_ptr  = (int*)wsb;            wsb = align16(wsb + (size_t)(N + 1) * 4);
    int*   cursor   = (int*)wsb;            wsb = align16(wsb + (size_t)N * 4);
    int*   blocksum = (int*)wsb;            wsb = align16(wsb + (size_t)SCAN_B * 4);
    int2*  csr_edge = (int2*)wsb;           wsb = align16(wsb + (size_t)E * 8);
    unsigned short* W1t = (unsigned short*)wsb;  wsb = align16(wsb + (size_t)F_IN * HF * 2);
    unsigned short* W2t = (unsigned short*)wsb;  wsb = align16(wsb + (size_t)HF * HF * 2);
    unsigned short* bufh = (unsigned short*)wsb; wsb = align16(wsb + (size_t)MP * HF * 2);
    unsigned short* bufa = (unsigned short*)wsb; wsb = align16(wsb + (size_t)MP * HF * 2);
    float* h3 = (float*)wsb;                wsb = align16(wsb + (size_t)N * OUT_F * 4);
    float* outf = (float*)d_out;

    const int TB = 256;
    const int nscan = (N + SCAN_B - 1) / SCAN_B;        // 196
    const int padcount = (MP - N) * HF;                 // bufa pad rows (feed GEMM2 as A)
    const int preptot = N + F_IN * HF + HF * HF + padcount;

    // --- prep: packed init + weight transposes + pad zero (one kernel) ---
    prep_kernel<<<(preptot + TB - 1) / TB, TB, 0, stream>>>(
        packed, W1, W1t, W2, W2t, bufa + (size_t)N * HF, N, padcount);

    // --- graph preprocessing (graph identical across all 3 layers) ---
    count_pack_kernel<<<(E + TB - 1) / TB, TB, 0, stream>>>(col, ew, packed, E);
    scan1_kernel<<<nscan, SCAN_B, 0, stream>>>(packed, csr_ptr, blocksum, N);
    scan3_dinv_kernel<<<nscan, SCAN_B, 0, stream>>>(csr_ptr, cursor, blocksum, packed, dinv, N, E, nscan);
    fill_kernel<<<(E + TB - 1) / TB, TB, 0, stream>>>(row, col, ew, dinv, cursor, csr_edge, E);

    dim3 ggrid(MP / 128, HF / 64);   // (391, 4)

    // --- layer 1 ---
    gemm_bf16_kernel<1><<<ggrid, TB, 0, stream>>>(x, W1t, bufh, N, F_IN, HF);
    agg_bn_relu_kernel<<<((size_t)N * 64 + TB - 1) / TB, TB, 0, stream>>>(
        bufh, csr_ptr, csr_edge, dinv, b1, g1, be1, m1, v1, bufa, N);

    // --- layer 2 ---
    gemm_bf16_kernel<0><<<ggrid, TB, 0, stream>>>(bufa, W2t, bufh, MP, HF, HF);
    agg_bn_relu_kernel<<<((size_t)N * 64 + TB - 1) / TB, TB, 0, stream>>>(
        bufh, csr_ptr, csr_edge, dinv, b2, g2, be2, m2, v2, bufa, N);

    // --- layer 3 ---
    gemv_out_kernel<<<((size_t)N * 64 + TB - 1) / TB, TB, 0, stream>>>(bufa, W3, h3, N);
    out_kernel<<<(N + TB - 1) / TB, TB, 0, stream>>>(h3, csr_ptr, csr_edge, dinv, b3, outf, N);
}